// Round 3
// baseline (1536.911 us; speedup 1.0000x reference)
//
#include <hip/hip_runtime.h>
#include <hip/hip_bf16.h>

// Round 3: fix workspace overflow (round 2 crash = device page fault,
// 271.5 MB carve > ws_size; round 1's 239.5 MB ran). New plan: 4 aliased
// 32MB activation slots + 64MB scores + 15.5MB weights = 207.5 MB peak.
// V projections store directly transposed (per-batch [DB][Nn]) -> no VT buf.
// f32 in/out per reference; bf16 MFMA internally. B=8, N=2048, DA=768, DB=1024.

#define AS1 __attribute__((address_space(1)))
#define AS3 __attribute__((address_space(3)))

typedef __attribute__((ext_vector_type(8))) short bf16x8;
typedef __attribute__((ext_vector_type(4))) float f32x4;

using bf = __hip_bfloat16;

#define BM 128
#define BN 128
#define BK 32

// C = alpha * A[M,K] @ BT[Nc,K]^T (+ bias f32) (+ resid f32 or bf16)
// A, BT row-major bf16. Batched via blockIdx.z (element strides sA,sB,sC).
// tstore=1: store bf16 transposed per 2048-row batch: [batch][col][row&2047].
__global__ __launch_bounds__(256) void gemm_bt(
    const bf* __restrict__ A, const bf* __restrict__ BT,
    const float* __restrict__ bias,
    const float* __restrict__ resid32, const bf* __restrict__ resid16,
    bf* __restrict__ C16, float* __restrict__ C32,
    int M, int Nc, int K, float alpha,
    long sA, long sB, long sC, int tstore)
{
    __shared__ short As[BM * BK];
    __shared__ short Bs[BN * BK];

    const int tid  = threadIdx.x;
    const int wave = tid >> 6;
    const int lane = tid & 63;
    const int m0 = blockIdx.y * BM;
    const int n0 = blockIdx.x * BN;
    const long zC = (long)blockIdx.z * sC;
    A  += (long)blockIdx.z * sA;
    BT += (long)blockIdx.z * sB;

    const int wm = wave >> 1, wn = wave & 1;   // wave -> 64x64 quadrant
    const int fl = lane & 15, qd = lane >> 4;

    f32x4 acc[4][4];
#pragma unroll
    for (int i = 0; i < 4; i++)
#pragma unroll
        for (int j = 0; j < 4; j++)
            acc[i][j] = (f32x4){0.f, 0.f, 0.f, 0.f};

    // Staging: tile 128 rows x 64 bytes (BK=32 bf16). Each wave stages 32 rows
    // via two 16-row wave-wide 16B global_load_lds. f = wave*2048 + lane*16.
    const int f0  = wave * 2048 + lane * 16;
    const int r0  = f0 >> 6;
    const int c0b = f0 & 63;
    const long ldb = (long)K * 2;   // row bytes for A and BT

    const char* gA = (const char*)A  + (long)(m0 + r0) * ldb + c0b;
    const char* gB = (const char*)BT + (long)(n0 + r0) * ldb + c0b;
    char* lA = (char*)As + wave * 2048;
    char* lB = (char*)Bs + wave * 2048;

    for (int k0 = 0; k0 < K; k0 += BK) {
        __builtin_amdgcn_global_load_lds((const AS1 void*)gA,              (AS3 void*)lA,          16, 0, 0);
        __builtin_amdgcn_global_load_lds((const AS1 void*)(gA + 16 * ldb),(AS3 void*)(lA + 1024), 16, 0, 0);
        __builtin_amdgcn_global_load_lds((const AS1 void*)gB,              (AS3 void*)lB,          16, 0, 0);
        __builtin_amdgcn_global_load_lds((const AS1 void*)(gB + 16 * ldb),(AS3 void*)(lB + 1024), 16, 0, 0);
        gA += BK * 2;
        gB += BK * 2;
        __syncthreads();   // drains vmcnt -> staging visible

        bf16x8 af[4], bfr[4];
#pragma unroll
        for (int i = 0; i < 4; i++) {
            af[i]  = *(const bf16x8*)(As + (wm * 64 + i * 16 + fl) * BK + qd * 8);
            bfr[i] = *(const bf16x8*)(Bs + (wn * 64 + i * 16 + fl) * BK + qd * 8);
        }
#pragma unroll
        for (int i = 0; i < 4; i++)
#pragma unroll
            for (int j = 0; j < 4; j++)
                acc[i][j] = __builtin_amdgcn_mfma_f32_16x16x32_bf16(af[i], bfr[j], acc[i][j], 0, 0, 0);
        __syncthreads();   // protect LDS before next staging
    }

    // Epilogue: C/D layout col = lane&15, row = qd*4 + r (verified m89/m91).
    const long ldc = Nc;
#pragma unroll
    for (int i = 0; i < 4; i++) {
#pragma unroll
        for (int j = 0; j < 4; j++) {
#pragma unroll
            for (int r = 0; r < 4; r++) {
                const int row = m0 + wm * 64 + i * 16 + qd * 4 + r;
                const int col = n0 + wn * 64 + j * 16 + fl;
                float v = acc[i][j][r] * alpha;
                if (bias) v += bias[col];
                if (tstore) {
                    // per-2048-row batch, transposed: [z][col][row&2047]
                    const long idx = (long)(row >> 11) * ((long)Nc * 2048)
                                   + (long)col * 2048 + (row & 2047);
                    C16[idx] = __float2bfloat16(v);
                } else {
                    const long idx = zC + (long)row * ldc + col;
                    if (resid32) v += resid32[idx];
                    if (resid16) v += __bfloat162float(resid16[idx]);
                    if (C16) C16[idx] = __float2bfloat16(v);
                    if (C32) C32[idx] = v;
                }
            }
        }
    }
}

// elementwise f32 -> bf16, n must be a multiple of 8
__global__ __launch_bounds__(256) void cast_f32_bf16(
    const float* __restrict__ in, bf* __restrict__ out, long n)
{
    long i = ((long)blockIdx.x * 256 + threadIdx.x) * 8;
    if (i >= n) return;
    float4 a = *(const float4*)(in + i);
    float4 b = *(const float4*)(in + i + 4);
    bf o[8] = {__float2bfloat16(a.x), __float2bfloat16(a.y),
               __float2bfloat16(a.z), __float2bfloat16(a.w),
               __float2bfloat16(b.x), __float2bfloat16(b.y),
               __float2bfloat16(b.z), __float2bfloat16(b.w)};
    *(bf16x8*)(out + i) = *(bf16x8*)o;
}

// W[R,C] f32 -> WT[C,R] bf16
__global__ __launch_bounds__(256) void transpose_f32_bf16(
    const float* __restrict__ in, bf* __restrict__ out, int R, int C)
{
    __shared__ bf t[32][33];
    const int c0 = blockIdx.x * 32, r0 = blockIdx.y * 32;
    const int tx = threadIdx.x, ty = threadIdx.y;
#pragma unroll
    for (int i = ty; i < 32; i += 8)
        t[i][tx] = __float2bfloat16(in[(long)(r0 + i) * C + c0 + tx]);
    __syncthreads();
#pragma unroll
    for (int i = ty; i < 32; i += 8)
        out[(long)(c0 + i) * R + r0 + tx] = t[tx][i];
}

// In-place row softmax over 2048 bf16 cols; one 256-thread block per row.
__global__ __launch_bounds__(256) void softmax_rows(bf* __restrict__ S)
{
    const long row = blockIdx.x;
    bf* p = S + row * 2048;
    const int tx = threadIdx.x;

    float v[8];
    float m = -3.0e38f;
#pragma unroll
    for (int i = 0; i < 8; i++) {
        v[i] = __bfloat162float(p[tx + 256 * i]);
        m = fmaxf(m, v[i]);
    }
    __shared__ float red[4];
#pragma unroll
    for (int o = 1; o < 64; o <<= 1) m = fmaxf(m, __shfl_xor(m, o, 64));
    if ((tx & 63) == 0) red[tx >> 6] = m;
    __syncthreads();
    m = fmaxf(fmaxf(red[0], red[1]), fmaxf(red[2], red[3]));

    float s = 0.f;
#pragma unroll
    for (int i = 0; i < 8; i++) { v[i] = __expf(v[i] - m); s += v[i]; }
#pragma unroll
    for (int o = 1; o < 64; o <<= 1) s += __shfl_xor(s, o, 64);
    __syncthreads();
    if ((tx & 63) == 0) red[tx >> 6] = s;
    __syncthreads();
    const float inv = 1.0f / (red[0] + red[1] + red[2] + red[3]);
#pragma unroll
    for (int i = 0; i < 8; i++) p[tx + 256 * i] = __float2bfloat16(v[i] * inv);
}

extern "C" void kernel_launch(void* const* d_in, const int* in_sizes, int n_in,
                              void* d_out, int out_size, void* d_ws, size_t ws_size,
                              hipStream_t stream)
{
    const int Bb = 8, Nn = 2048, DA = 768, DB = 1024;
    const long Mt = (long)Bb * Nn;   // 16384 tokens

    const float* x_a   = (const float*)d_in[0];
    const float* x_b   = (const float*)d_in[1];
    const float* sa_wq = (const float*)d_in[2];  const float* sa_bq = (const float*)d_in[3];
    const float* sa_wk = (const float*)d_in[4];  const float* sa_bk = (const float*)d_in[5];
    const float* sa_wv = (const float*)d_in[6];  const float* sa_bv = (const float*)d_in[7];
    const float* sa_wo = (const float*)d_in[8];  const float* sa_bo = (const float*)d_in[9];
    const float* ca_wq = (const float*)d_in[10]; const float* ca_bq = (const float*)d_in[11];
    const float* ca_wk = (const float*)d_in[12]; const float* ca_bk = (const float*)d_in[13];
    const float* ca_wv = (const float*)d_in[14]; const float* ca_bv = (const float*)d_in[15];
    const float* ca_wo = (const float*)d_in[16]; const float* ca_bo = (const float*)d_in[17];
    float* out = (float*)d_out;
    (void)in_sizes; (void)n_in; (void)out_size; (void)ws_size;

    // workspace carve-up (256B aligned): peak 207.5 MB
    char* ws = (char*)d_ws;
    size_t off = 0;
    auto alloc = [&](size_t bytes) -> bf* {
        bf* p = (bf*)(ws + off);
        off += (bytes + 255) & ~(size_t)255;
        return p;
    };
    bf* wqT  = alloc((size_t)DB * DB * 2);
    bf* wkT  = alloc((size_t)DB * DB * 2);
    bf* wvT  = alloc((size_t)DB * DB * 2);
    bf* woT  = alloc((size_t)DB * DB * 2);
    bf* cwqT = alloc((size_t)DB * DA * 2);   // [DB, DA]
    bf* cwkT = alloc((size_t)DB * DB * 2);
    bf* cwvT = alloc((size_t)DB * DB * 2);
    bf* cwoT = alloc((size_t)DB * DB * 2);
    bf* slA  = alloc((size_t)Mt * DB * 2);   // xbB -> xaB -> VcT
    bf* slQ  = alloc((size_t)Mt * DB * 2);   // Q   -> Xb
    bf* slK  = alloc((size_t)Mt * DB * 2);   // K   -> attn -> Qc
    bf* slV  = alloc((size_t)Mt * DB * 2);   // VT  -> Kc   -> ca_attn
    bf* S    = alloc((size_t)Bb * Nn * Nn * 2);

    const dim3 tb(32, 8);
    const dim3 blk(256);
    const long sQ = (long)Nn * DB;   // per-batch stride of [N,DB] / [DB,N]
    const long sS = (long)Nn * Nn;

    // ---- ingestion: weight transposes (f32 -> bf16) ----
    transpose_f32_bf16<<<dim3(DB/32, DB/32), tb, 0, stream>>>(sa_wq, wqT,  DB, DB);
    transpose_f32_bf16<<<dim3(DB/32, DB/32), tb, 0, stream>>>(sa_wk, wkT,  DB, DB);
    transpose_f32_bf16<<<dim3(DB/32, DB/32), tb, 0, stream>>>(sa_wv, wvT,  DB, DB);
    transpose_f32_bf16<<<dim3(DB/32, DB/32), tb, 0, stream>>>(sa_wo, woT,  DB, DB);
    transpose_f32_bf16<<<dim3(DB/32, DA/32), tb, 0, stream>>>(ca_wq, cwqT, DA, DB);
    transpose_f32_bf16<<<dim3(DB/32, DB/32), tb, 0, stream>>>(ca_wk, cwkT, DB, DB);
    transpose_f32_bf16<<<dim3(DB/32, DB/32), tb, 0, stream>>>(ca_wv, cwvT, DB, DB);
    transpose_f32_bf16<<<dim3(DB/32, DB/32), tb, 0, stream>>>(ca_wo, cwoT, DB, DB);

    // ---- self-attention ----
    cast_f32_bf16<<<dim3((unsigned)(Mt * DB / 8 / 256)), blk, 0, stream>>>(x_b, slA, Mt * DB);
    gemm_bt<<<dim3(DB/BN, Mt/BM, 1), blk, 0, stream>>>(slA, wqT, sa_bq, nullptr, nullptr, slQ, nullptr, Mt, DB, DB, 1.0f, 0, 0, 0, 0);
    gemm_bt<<<dim3(DB/BN, Mt/BM, 1), blk, 0, stream>>>(slA, wkT, sa_bk, nullptr, nullptr, slK, nullptr, Mt, DB, DB, 1.0f, 0, 0, 0, 0);
    // V projection, stored transposed per batch: slV[z][d][n]
    gemm_bt<<<dim3(DB/BN, Mt/BM, 1), blk, 0, stream>>>(slA, wvT, sa_bv, nullptr, nullptr, slV, nullptr, Mt, DB, DB, 1.0f, 0, 0, 0, 1);
    // scores = (Q @ K^T) / 32
    gemm_bt<<<dim3(Nn/BN, Nn/BM, Bb), blk, 0, stream>>>(slQ, slK, nullptr, nullptr, nullptr, S, nullptr, Nn, Nn, DB, 0.03125f, sQ, sQ, sS, 0);
    softmax_rows<<<dim3((unsigned)(Bb * Nn)), blk, 0, stream>>>(S);
    // attn = P @ V (VT as B^T) -> slK (K dead)
    gemm_bt<<<dim3(DB/BN, Nn/BM, Bb), blk, 0, stream>>>(S, slV, nullptr, nullptr, nullptr, slK, nullptr, Nn, DB, Nn, 1.0f, sS, sQ, sQ, 0);
    // x_b_new = x_b(f32) + attn @ Wo + bo -> slQ (Q dead)
    gemm_bt<<<dim3(DB/BN, Mt/BM, 1), blk, 0, stream>>>(slK, woT, sa_bo, x_b, nullptr, slQ, nullptr, Mt, DB, DB, 1.0f, 0, 0, 0, 0);

    // ---- cross-attention ----
    cast_f32_bf16<<<dim3((unsigned)(Mt * DA / 8 / 256)), blk, 0, stream>>>(x_a, slA, Mt * DA);  // xaB -> slA (xbB dead)
    gemm_bt<<<dim3(DB/BN, Mt/BM, 1), blk, 0, stream>>>(slA, cwqT, ca_bq, nullptr, nullptr, slK, nullptr, Mt, DB, DA, 1.0f, 0, 0, 0, 0); // Qc -> slK (attn dead)
    gemm_bt<<<dim3(DB/BN, Mt/BM, 1), blk, 0, stream>>>(slQ, cwkT, ca_bk, nullptr, nullptr, slV, nullptr, Mt, DB, DB, 1.0f, 0, 0, 0, 0); // Kc -> slV (VT dead)
    // Vc projection, transposed -> slA (xaB dead)
    gemm_bt<<<dim3(DB/BN, Mt/BM, 1), blk, 0, stream>>>(slQ, cwvT, ca_bv, nullptr, nullptr, slA, nullptr, Mt, DB, DB, 1.0f, 0, 0, 0, 1);
    // scores = (Qc @ Kc^T) / sqrt(768)
    gemm_bt<<<dim3(Nn/BN, Nn/BM, Bb), blk, 0, stream>>>(slK, slV, nullptr, nullptr, nullptr, S, nullptr, Nn, Nn, DB, 0.036084391824351615f, sQ, sQ, sS, 0);
    softmax_rows<<<dim3((unsigned)(Bb * Nn)), blk, 0, stream>>>(S);
    // ca_attn = P @ Vc -> slV (Kc dead)
    gemm_bt<<<dim3(DB/BN, Nn/BM, Bb), blk, 0, stream>>>(S, slA, nullptr, nullptr, nullptr, slV, nullptr, Nn, DB, Nn, 1.0f, sS, sQ, sQ, 0);
    // out(f32) = x_b_new(bf16, slQ) + ca_attn @ Wo + bo
    gemm_bt<<<dim3(DB/BN, Mt/BM, 1), blk, 0, stream>>>(slV, cwoT, ca_bo, nullptr, slQ, nullptr, out, Mt, DB, DB, 1.0f, 0, 0, 0, 0);
}

// Round 4
// 1403.448 us; speedup vs baseline: 1.0951x; 1.0951x over previous
//
#include <hip/hip_runtime.h>
#include <hip/hip_bf16.h>

// Round 4: fuse QKV projections (Nc=3072) and cross K/V (Nc=2048) into single
// GEMMs with a segmented epilogue. Round-3 counters showed the 5 DB x DB
// projection dispatches latency-bound: MfmaUtil 8.2% (=206 TF), occupancy 22%
// (grid 1024 = 4 blocks/CU), FETCH 166 MB vs 34 MB unique. Fusion -> grid
// 3072 (7 blocks/CU, VGPR-capped), 12 GEMM dispatches -> 9.
// f32 in/out per reference; bf16 MFMA internally. B=8, N=2048, DA=768, DB=1024.

#define AS1 __attribute__((address_space(1)))
#define AS3 __attribute__((address_space(3)))

typedef __attribute__((ext_vector_type(8))) short bf16x8;
typedef __attribute__((ext_vector_type(4))) float f32x4;

using bf = __hip_bfloat16;

#define BM 128
#define BN 128
#define BK 32

// C = alpha * A[M,K] @ BT[Nc,K]^T.
// nseg==1: (+bias)(+resid32/resid16) -> C16 and/or C32, ldc=Nc, tstore bit0.
// nseg>1 : output split into 1024-col segments -> {C16,C16b,C16c} with biases
//          {bias,biasB,biasC}; tstore bit s stores segment s transposed per
//          2048-row batch: [z][col][row&2047]. (128-tile never straddles a
//          segment since 1024 % 128 == 0.)
__global__ __launch_bounds__(256) void gemm_bt(
    const bf* __restrict__ A, const bf* __restrict__ BT,
    const float* __restrict__ bias, const float* __restrict__ biasB,
    const float* __restrict__ biasC,
    const float* __restrict__ resid32, const bf* __restrict__ resid16,
    bf* __restrict__ C16, bf* __restrict__ C16b, bf* __restrict__ C16c,
    float* __restrict__ C32,
    int M, int Nc, int K, float alpha,
    long sA, long sB, long sC, int tstore, int nseg)
{
    __shared__ short As[BM * BK];
    __shared__ short Bs[BN * BK];

    const int tid  = threadIdx.x;
    const int wave = tid >> 6;
    const int lane = tid & 63;
    const int m0 = blockIdx.y * BM;
    const int n0 = blockIdx.x * BN;
    const long zC = (long)blockIdx.z * sC;
    A  += (long)blockIdx.z * sA;
    BT += (long)blockIdx.z * sB;

    const int wm = wave >> 1, wn = wave & 1;   // wave -> 64x64 quadrant
    const int fl = lane & 15, qd = lane >> 4;

    f32x4 acc[4][4];
#pragma unroll
    for (int i = 0; i < 4; i++)
#pragma unroll
        for (int j = 0; j < 4; j++)
            acc[i][j] = (f32x4){0.f, 0.f, 0.f, 0.f};

    // Staging: tile 128 rows x 64 bytes (BK=32 bf16). Each wave stages 32 rows
    // via two 16-row wave-wide 16B global_load_lds. f = wave*2048 + lane*16.
    const int f0  = wave * 2048 + lane * 16;
    const int r0  = f0 >> 6;
    const int c0b = f0 & 63;
    const long ldb = (long)K * 2;   // row bytes for A and BT

    const char* gA = (const char*)A  + (long)(m0 + r0) * ldb + c0b;
    const char* gB = (const char*)BT + (long)(n0 + r0) * ldb + c0b;
    char* lA = (char*)As + wave * 2048;
    char* lB = (char*)Bs + wave * 2048;

    for (int k0 = 0; k0 < K; k0 += BK) {
        __builtin_amdgcn_global_load_lds((const AS1 void*)gA,              (AS3 void*)lA,          16, 0, 0);
        __builtin_amdgcn_global_load_lds((const AS1 void*)(gA + 16 * ldb),(AS3 void*)(lA + 1024), 16, 0, 0);
        __builtin_amdgcn_global_load_lds((const AS1 void*)gB,              (AS3 void*)lB,          16, 0, 0);
        __builtin_amdgcn_global_load_lds((const AS1 void*)(gB + 16 * ldb),(AS3 void*)(lB + 1024), 16, 0, 0);
        gA += BK * 2;
        gB += BK * 2;
        __syncthreads();   // drains vmcnt -> staging visible

        bf16x8 af[4], bfr[4];
#pragma unroll
        for (int i = 0; i < 4; i++) {
            af[i]  = *(const bf16x8*)(As + (wm * 64 + i * 16 + fl) * BK + qd * 8);
            bfr[i] = *(const bf16x8*)(Bs + (wn * 64 + i * 16 + fl) * BK + qd * 8);
        }
#pragma unroll
        for (int i = 0; i < 4; i++)
#pragma unroll
            for (int j = 0; j < 4; j++)
                acc[i][j] = __builtin_amdgcn_mfma_f32_16x16x32_bf16(af[i], bfr[j], acc[i][j], 0, 0, 0);
        __syncthreads();   // protect LDS before next staging
    }

    // Epilogue: C/D layout col = lane&15, row = qd*4 + r (verified m89/m91).
    if (nseg == 1) {
        const long ldc = Nc;
#pragma unroll
        for (int i = 0; i < 4; i++) {
#pragma unroll
            for (int j = 0; j < 4; j++) {
#pragma unroll
                for (int r = 0; r < 4; r++) {
                    const int row = m0 + wm * 64 + i * 16 + qd * 4 + r;
                    const int col = n0 + wn * 64 + j * 16 + fl;
                    float v = acc[i][j][r] * alpha;
                    if (bias) v += bias[col];
                    if (tstore & 1) {
                        const long idx = (long)(row >> 11) * ((long)Nc * 2048)
                                       + (long)col * 2048 + (row & 2047);
                        C16[idx] = __float2bfloat16(v);
                    } else {
                        const long idx = zC + (long)row * ldc + col;
                        if (resid32) v += resid32[idx];
                        if (resid16) v += __bfloat162float(resid16[idx]);
                        if (C16) C16[idx] = __float2bfloat16(v);
                        if (C32) C32[idx] = v;
                    }
                }
            }
        }
    } else {
        const int seg = n0 >> 10;
        bf* dst = (seg == 0) ? C16 : ((seg == 1) ? C16b : C16c);
        const float* bseg = (seg == 0) ? bias : ((seg == 1) ? biasB : biasC);
        const int trans = (tstore >> seg) & 1;
        const int cb = n0 & 1023;
#pragma unroll
        for (int i = 0; i < 4; i++) {
#pragma unroll
            for (int j = 0; j < 4; j++) {
#pragma unroll
                for (int r = 0; r < 4; r++) {
                    const int row = m0 + wm * 64 + i * 16 + qd * 4 + r;
                    const int col = cb + wn * 64 + j * 16 + fl;
                    float v = acc[i][j][r] * alpha + bseg[col];
                    const long idx = trans
                        ? (long)(row >> 11) * (1024L * 2048) + (long)col * 2048 + (row & 2047)
                        : (long)row * 1024 + col;
                    dst[idx] = __float2bfloat16(v);
                }
            }
        }
    }
}

// elementwise f32 -> bf16, n must be a multiple of 8
__global__ __launch_bounds__(256) void cast_f32_bf16(
    const float* __restrict__ in, bf* __restrict__ out, long n)
{
    long i = ((long)blockIdx.x * 256 + threadIdx.x) * 8;
    if (i >= n) return;
    float4 a = *(const float4*)(in + i);
    float4 b = *(const float4*)(in + i + 4);
    bf o[8] = {__float2bfloat16(a.x), __float2bfloat16(a.y),
               __float2bfloat16(a.z), __float2bfloat16(a.w),
               __float2bfloat16(b.x), __float2bfloat16(b.y),
               __float2bfloat16(b.z), __float2bfloat16(b.w)};
    *(bf16x8*)(out + i) = *(bf16x8*)o;
}

// W[R,C] f32 -> WT[C,R] bf16
__global__ __launch_bounds__(256) void transpose_f32_bf16(
    const float* __restrict__ in, bf* __restrict__ out, int R, int C)
{
    __shared__ bf t[32][33];
    const int c0 = blockIdx.x * 32, r0 = blockIdx.y * 32;
    const int tx = threadIdx.x, ty = threadIdx.y;
#pragma unroll
    for (int i = ty; i < 32; i += 8)
        t[i][tx] = __float2bfloat16(in[(long)(r0 + i) * C + c0 + tx]);
    __syncthreads();
#pragma unroll
    for (int i = ty; i < 32; i += 8)
        out[(long)(c0 + i) * R + r0 + tx] = t[tx][i];
}

// In-place row softmax over 2048 bf16 cols; one 256-thread block per row.
__global__ __launch_bounds__(256) void softmax_rows(bf* __restrict__ S)
{
    const long row = blockIdx.x;
    bf* p = S + row * 2048;
    const int tx = threadIdx.x;

    float v[8];
    float m = -3.0e38f;
#pragma unroll
    for (int i = 0; i < 8; i++) {
        v[i] = __bfloat162float(p[tx + 256 * i]);
        m = fmaxf(m, v[i]);
    }
    __shared__ float red[4];
#pragma unroll
    for (int o = 1; o < 64; o <<= 1) m = fmaxf(m, __shfl_xor(m, o, 64));
    if ((tx & 63) == 0) red[tx >> 6] = m;
    __syncthreads();
    m = fmaxf(fmaxf(red[0], red[1]), fmaxf(red[2], red[3]));

    float s = 0.f;
#pragma unroll
    for (int i = 0; i < 8; i++) { v[i] = __expf(v[i] - m); s += v[i]; }
#pragma unroll
    for (int o = 1; o < 64; o <<= 1) s += __shfl_xor(s, o, 64);
    __syncthreads();
    if ((tx & 63) == 0) red[tx >> 6] = s;
    __syncthreads();
    const float inv = 1.0f / (red[0] + red[1] + red[2] + red[3]);
#pragma unroll
    for (int i = 0; i < 8; i++) p[tx + 256 * i] = __float2bfloat16(v[i] * inv);
}

extern "C" void kernel_launch(void* const* d_in, const int* in_sizes, int n_in,
                              void* d_out, int out_size, void* d_ws, size_t ws_size,
                              hipStream_t stream)
{
    const int Bb = 8, Nn = 2048, DA = 768, DB = 1024;
    const long Mt = (long)Bb * Nn;   // 16384 tokens

    const float* x_a   = (const float*)d_in[0];
    const float* x_b   = (const float*)d_in[1];
    const float* sa_wq = (const float*)d_in[2];  const float* sa_bq = (const float*)d_in[3];
    const float* sa_wk = (const float*)d_in[4];  const float* sa_bk = (const float*)d_in[5];
    const float* sa_wv = (const float*)d_in[6];  const float* sa_bv = (const float*)d_in[7];
    const float* sa_wo = (const float*)d_in[8];  const float* sa_bo = (const float*)d_in[9];
    const float* ca_wq = (const float*)d_in[10]; const float* ca_bq = (const float*)d_in[11];
    const float* ca_wk = (const float*)d_in[12]; const float* ca_bk = (const float*)d_in[13];
    const float* ca_wv = (const float*)d_in[14]; const float* ca_bv = (const float*)d_in[15];
    const float* ca_wo = (const float*)d_in[16]; const float* ca_bo = (const float*)d_in[17];
    float* out = (float*)d_out;
    (void)in_sizes; (void)n_in; (void)out_size; (void)ws_size;

    // workspace carve-up (256B aligned): peak 207.5 MB (round-3 layout proven)
    char* ws = (char*)d_ws;
    size_t off = 0;
    auto alloc = [&](size_t bytes) -> bf* {
        bf* p = (bf*)(ws + off);
        off += (bytes + 255) & ~(size_t)255;
        return p;
    };
    bf* wqkvT = alloc((size_t)3 * DB * DB * 2);  // [3072,1024] concat q,k,v
    bf* woT   = alloc((size_t)DB * DB * 2);
    bf* cwqT  = alloc((size_t)DB * DA * 2);      // [1024,768]
    bf* ckvT  = alloc((size_t)2 * DB * DB * 2);  // [2048,1024] concat k,v
    bf* cwoT  = alloc((size_t)DB * DB * 2);
    bf* slA   = alloc((size_t)Mt * DB * 2);      // xbB -> xaB -> VcT
    bf* slQ   = alloc((size_t)Mt * DB * 2);      // Q   -> Xb
    bf* slK   = alloc((size_t)Mt * DB * 2);      // K   -> attn -> Qc
    bf* slV   = alloc((size_t)Mt * DB * 2);      // VT  -> Kc
    bf* S     = alloc((size_t)Bb * Nn * Nn * 2);

    const dim3 tb(32, 8);
    const dim3 blk(256);
    const long sQ = (long)Nn * DB;   // per-batch stride of [N,DB] / [DB,N]
    const long sS = (long)Nn * Nn;
    const float* nf = nullptr;
    const bf*    nb = nullptr;
    bf*          no = nullptr;

    // ---- ingestion: weight transposes (f32 -> bf16), concat layouts ----
    transpose_f32_bf16<<<dim3(DB/32, DB/32), tb, 0, stream>>>(sa_wq, wqkvT,                 DB, DB);
    transpose_f32_bf16<<<dim3(DB/32, DB/32), tb, 0, stream>>>(sa_wk, wqkvT + (size_t)DB*DB, DB, DB);
    transpose_f32_bf16<<<dim3(DB/32, DB/32), tb, 0, stream>>>(sa_wv, wqkvT + (size_t)2*DB*DB, DB, DB);
    transpose_f32_bf16<<<dim3(DB/32, DB/32), tb, 0, stream>>>(sa_wo, woT,  DB, DB);
    transpose_f32_bf16<<<dim3(DB/32, DA/32), tb, 0, stream>>>(ca_wq, cwqT, DA, DB);
    transpose_f32_bf16<<<dim3(DB/32, DB/32), tb, 0, stream>>>(ca_wk, ckvT,                 DB, DB);
    transpose_f32_bf16<<<dim3(DB/32, DB/32), tb, 0, stream>>>(ca_wv, ckvT + (size_t)DB*DB, DB, DB);
    transpose_f32_bf16<<<dim3(DB/32, DB/32), tb, 0, stream>>>(ca_wo, cwoT, DB, DB);

    // ---- self-attention ----
    cast_f32_bf16<<<dim3((unsigned)(Mt * DB / 8 / 256)), blk, 0, stream>>>(x_b, slA, Mt * DB);
    // fused QKV: Q->slQ, K->slK, V->slV (transposed per batch)
    gemm_bt<<<dim3(3*DB/BN, Mt/BM, 1), blk, 0, stream>>>(
        slA, wqkvT, sa_bq, sa_bk, sa_bv, nf, nb, slQ, slK, slV, nullptr,
        (int)Mt, 3*DB, DB, 1.0f, 0, 0, 0, 0b100, 3);
    // scores = (Q @ K^T) / 32
    gemm_bt<<<dim3(Nn/BN, Nn/BM, Bb), blk, 0, stream>>>(
        slQ, slK, nf, nf, nf, nf, nb, S, no, no, nullptr,
        Nn, Nn, DB, 0.03125f, sQ, sQ, sS, 0, 1);
    softmax_rows<<<dim3((unsigned)(Bb * Nn)), blk, 0, stream>>>(S);
    // attn = P @ V (VT as B^T) -> slK (K dead)
    gemm_bt<<<dim3(DB/BN, Nn/BM, Bb), blk, 0, stream>>>(
        S, slV, nf, nf, nf, nf, nb, slK, no, no, nullptr,
        Nn, DB, Nn, 1.0f, sS, sQ, sQ, 0, 1);
    // x_b_new = x_b(f32) + attn @ Wo + bo -> slQ (Q dead)
    gemm_bt<<<dim3(DB/BN, Mt/BM, 1), blk, 0, stream>>>(
        slK, woT, sa_bo, nf, nf, x_b, nb, slQ, no, no, nullptr,
        (int)Mt, DB, DB, 1.0f, 0, 0, 0, 0, 1);

    // ---- cross-attention ----
    cast_f32_bf16<<<dim3((unsigned)(Mt * DA / 8 / 256)), blk, 0, stream>>>(x_a, slA, Mt * DA);
    // Qc = xa @ cwq -> slK (attn dead)
    gemm_bt<<<dim3(DB/BN, Mt/BM, 1), blk, 0, stream>>>(
        slA, cwqT, ca_bq, nf, nf, nf, nb, slK, no, no, nullptr,
        (int)Mt, DB, DA, 1.0f, 0, 0, 0, 0, 1);
    // fused cKV from Xb(slQ): Kc->slV (VT dead), Vc->slA transposed (xaB dead)
    gemm_bt<<<dim3(2*DB/BN, Mt/BM, 1), blk, 0, stream>>>(
        slQ, ckvT, ca_bk, ca_bv, nf, nf, nb, slV, slA, no, nullptr,
        (int)Mt, 2*DB, DB, 1.0f, 0, 0, 0, 0b10, 2);
    // scores = (Qc @ Kc^T) / sqrt(768)
    gemm_bt<<<dim3(Nn/BN, Nn/BM, Bb), blk, 0, stream>>>(
        slK, slV, nf, nf, nf, nf, nb, S, no, no, nullptr,
        Nn, Nn, DB, 0.036084391824351615f, sQ, sQ, sS, 0, 1);
    softmax_rows<<<dim3((unsigned)(Bb * Nn)), blk, 0, stream>>>(S);
    // ca_attn = P @ Vc -> slV (Kc dead)
    gemm_bt<<<dim3(DB/BN, Nn/BM, Bb), blk, 0, stream>>>(
        S, slA, nf, nf, nf, nf, nb, slV, no, no, nullptr,
        Nn, DB, Nn, 1.0f, sS, sQ, sQ, 0, 1);
    // out(f32) = x_b_new(bf16, slQ) + ca_attn @ Wo + bo
    gemm_bt<<<dim3(DB/BN, Mt/BM, 1), blk, 0, stream>>>(
        slV, cwoT, ca_bo, nf, nf, nf, slQ, no, no, no, out,
        (int)Mt, DB, DB, 1.0f, 0, 0, 0, 0, 1);
}

// Round 5
// 1386.722 us; speedup vs baseline: 1.1083x; 1.0121x over previous
//
#include <hip/hip_runtime.h>
#include <hip/hip_bf16.h>

// Round 5: kill LDS bank conflicts in the shared GEMM core via XOR-swizzled
// chunk layout. Round-4 PMC: SQ_LDS_BANK_CONFLICT=1.26e7/dispatch over 3.1M
// ds_read_b128 = +4 cyc/read on 12 base; unswizzled 64B-row layout makes a
// 16-lane read group hit only groups {qd, qd+4} of 8 quad-bank groups (8-way).
// Fix: global_load_lds dest is fixed (base+lane*16), but the global SOURCE is
// per-lane — fetch global chunk c of row R into slot s=(c+R+(R>>2))&3; read
// chunk qd of row R from slot (qd+R+(R>>2))&3. Enumeration: each group hit
// exactly 2x per 16-lane read (2-way = free, m136).
// f32 in/out per reference; bf16 MFMA internally. B=8, N=2048, DA=768, DB=1024.

#define AS1 __attribute__((address_space(1)))
#define AS3 __attribute__((address_space(3)))

typedef __attribute__((ext_vector_type(8))) short bf16x8;
typedef __attribute__((ext_vector_type(4))) float f32x4;

using bf = __hip_bfloat16;

#define BM 128
#define BN 128
#define BK 32

// C = alpha * A[M,K] @ BT[Nc,K]^T.
// nseg==1: (+bias)(+resid32/resid16) -> C16 and/or C32, ldc=Nc, tstore bit0.
// nseg>1 : output split into 1024-col segments -> {C16,C16b,C16c} with biases
//          {bias,biasB,biasC}; tstore bit s stores segment s transposed per
//          2048-row batch: [z][col][row&2047]. (128-tile never straddles a
//          segment since 1024 % 128 == 0.)
__global__ __launch_bounds__(256) void gemm_bt(
    const bf* __restrict__ A, const bf* __restrict__ BT,
    const float* __restrict__ bias, const float* __restrict__ biasB,
    const float* __restrict__ biasC,
    const float* __restrict__ resid32, const bf* __restrict__ resid16,
    bf* __restrict__ C16, bf* __restrict__ C16b, bf* __restrict__ C16c,
    float* __restrict__ C32,
    int M, int Nc, int K, float alpha,
    long sA, long sB, long sC, int tstore, int nseg)
{
    __shared__ short As[BM * BK];
    __shared__ short Bs[BN * BK];

    const int tid  = threadIdx.x;
    const int wave = tid >> 6;
    const int lane = tid & 63;
    const int m0 = blockIdx.y * BM;
    const int n0 = blockIdx.x * BN;
    const long zC = (long)blockIdx.z * sC;
    A  += (long)blockIdx.z * sA;
    BT += (long)blockIdx.z * sB;

    const int wm = wave >> 1, wn = wave & 1;   // wave -> 64x64 quadrant
    const int fl = lane & 15, qd = lane >> 4;

    f32x4 acc[4][4];
#pragma unroll
    for (int i = 0; i < 4; i++)
#pragma unroll
        for (int j = 0; j < 4; j++)
            acc[i][j] = (f32x4){0.f, 0.f, 0.f, 0.f};

    // Staging (swizzled): tile 128 rows x 64 B (4 chunks of 16 B per row).
    // Wave w stages rows [w*32, w*32+32): lane l -> LDS slot (R, l&3) with
    // R = w*32 + (l>>2) (+16 for the second load). That slot must hold global
    // chunk c = ((l&3) - R - (R>>2)) & 3.
    const int R1 = wave * 32 + (lane >> 2);
    const int R2 = R1 + 16;
    const int sl = lane & 3;
    const int c1 = (sl - R1 - (R1 >> 2)) & 3;
    const int c2 = (sl - R2 - (R2 >> 2)) & 3;
    const long ldb = (long)K * 2;   // row bytes for A and BT

    const char* gA1 = (const char*)A  + (long)(m0 + R1) * ldb + c1 * 16;
    const char* gA2 = (const char*)A  + (long)(m0 + R2) * ldb + c2 * 16;
    const char* gB1 = (const char*)BT + (long)(n0 + R1) * ldb + c1 * 16;
    const char* gB2 = (const char*)BT + (long)(n0 + R2) * ldb + c2 * 16;
    char* lA = (char*)As + wave * 2048;
    char* lB = (char*)Bs + wave * 2048;

    for (int k0 = 0; k0 < K; k0 += BK) {
        __builtin_amdgcn_global_load_lds((const AS1 void*)gA1, (AS3 void*)lA,          16, 0, 0);
        __builtin_amdgcn_global_load_lds((const AS1 void*)gA2, (AS3 void*)(lA + 1024), 16, 0, 0);
        __builtin_amdgcn_global_load_lds((const AS1 void*)gB1, (AS3 void*)lB,          16, 0, 0);
        __builtin_amdgcn_global_load_lds((const AS1 void*)gB2, (AS3 void*)(lB + 1024), 16, 0, 0);
        gA1 += BK * 2; gA2 += BK * 2; gB1 += BK * 2; gB2 += BK * 2;
        __syncthreads();   // drains vmcnt -> staging visible

        bf16x8 af[4], bfr[4];
#pragma unroll
        for (int i = 0; i < 4; i++) {
            const int RA = wm * 64 + i * 16 + fl;
            const int RB = wn * 64 + i * 16 + fl;
            const int sA16 = (qd + RA + (RA >> 2)) & 3;   // swizzled slot
            const int sB16 = (qd + RB + (RB >> 2)) & 3;
            af[i]  = *(const bf16x8*)(As + RA * 32 + sA16 * 8);
            bfr[i] = *(const bf16x8*)(Bs + RB * 32 + sB16 * 8);
        }
#pragma unroll
        for (int i = 0; i < 4; i++)
#pragma unroll
            for (int j = 0; j < 4; j++)
                acc[i][j] = __builtin_amdgcn_mfma_f32_16x16x32_bf16(af[i], bfr[j], acc[i][j], 0, 0, 0);
        __syncthreads();   // protect LDS before next staging
    }

    // Epilogue: C/D layout col = lane&15, row = qd*4 + r (verified m89/m91).
    if (nseg == 1) {
        const long ldc = Nc;
#pragma unroll
        for (int i = 0; i < 4; i++) {
#pragma unroll
            for (int j = 0; j < 4; j++) {
#pragma unroll
                for (int r = 0; r < 4; r++) {
                    const int row = m0 + wm * 64 + i * 16 + qd * 4 + r;
                    const int col = n0 + wn * 64 + j * 16 + fl;
                    float v = acc[i][j][r] * alpha;
                    if (bias) v += bias[col];
                    if (tstore & 1) {
                        const long idx = (long)(row >> 11) * ((long)Nc * 2048)
                                       + (long)col * 2048 + (row & 2047);
                        C16[idx] = __float2bfloat16(v);
                    } else {
                        const long idx = zC + (long)row * ldc + col;
                        if (resid32) v += resid32[idx];
                        if (resid16) v += __bfloat162float(resid16[idx]);
                        if (C16) C16[idx] = __float2bfloat16(v);
                        if (C32) C32[idx] = v;
                    }
                }
            }
        }
    } else {
        const int seg = n0 >> 10;
        bf* dst = (seg == 0) ? C16 : ((seg == 1) ? C16b : C16c);
        const float* bseg = (seg == 0) ? bias : ((seg == 1) ? biasB : biasC);
        const int trans = (tstore >> seg) & 1;
        const int cb = n0 & 1023;
#pragma unroll
        for (int i = 0; i < 4; i++) {
#pragma unroll
            for (int j = 0; j < 4; j++) {
#pragma unroll
                for (int r = 0; r < 4; r++) {
                    const int row = m0 + wm * 64 + i * 16 + qd * 4 + r;
                    const int col = cb + wn * 64 + j * 16 + fl;
                    float v = acc[i][j][r] * alpha + bseg[col];
                    const long idx = trans
                        ? (long)(row >> 11) * (1024L * 2048) + (long)col * 2048 + (row & 2047)
                        : (long)row * 1024 + col;
                    dst[idx] = __float2bfloat16(v);
                }
            }
        }
    }
}

// elementwise f32 -> bf16, n must be a multiple of 8
__global__ __launch_bounds__(256) void cast_f32_bf16(
    const float* __restrict__ in, bf* __restrict__ out, long n)
{
    long i = ((long)blockIdx.x * 256 + threadIdx.x) * 8;
    if (i >= n) return;
    float4 a = *(const float4*)(in + i);
    float4 b = *(const float4*)(in + i + 4);
    bf o[8] = {__float2bfloat16(a.x), __float2bfloat16(a.y),
               __float2bfloat16(a.z), __float2bfloat16(a.w),
               __float2bfloat16(b.x), __float2bfloat16(b.y),
               __float2bfloat16(b.z), __float2bfloat16(b.w)};
    *(bf16x8*)(out + i) = *(bf16x8*)o;
}

// W[R,C] f32 -> WT[C,R] bf16
__global__ __launch_bounds__(256) void transpose_f32_bf16(
    const float* __restrict__ in, bf* __restrict__ out, int R, int C)
{
    __shared__ bf t[32][33];
    const int c0 = blockIdx.x * 32, r0 = blockIdx.y * 32;
    const int tx = threadIdx.x, ty = threadIdx.y;
#pragma unroll
    for (int i = ty; i < 32; i += 8)
        t[i][tx] = __float2bfloat16(in[(long)(r0 + i) * C + c0 + tx]);
    __syncthreads();
#pragma unroll
    for (int i = ty; i < 32; i += 8)
        out[(long)(c0 + i) * R + r0 + tx] = t[tx][i];
}

// In-place row softmax over 2048 bf16 cols; one 256-thread block per row.
__global__ __launch_bounds__(256) void softmax_rows(bf* __restrict__ S)
{
    const long row = blockIdx.x;
    bf* p = S + row * 2048;
    const int tx = threadIdx.x;

    float v[8];
    float m = -3.0e38f;
#pragma unroll
    for (int i = 0; i < 8; i++) {
        v[i] = __bfloat162float(p[tx + 256 * i]);
        m = fmaxf(m, v[i]);
    }
    __shared__ float red[4];
#pragma unroll
    for (int o = 1; o < 64; o <<= 1) m = fmaxf(m, __shfl_xor(m, o, 64));
    if ((tx & 63) == 0) red[tx >> 6] = m;
    __syncthreads();
    m = fmaxf(fmaxf(red[0], red[1]), fmaxf(red[2], red[3]));

    float s = 0.f;
#pragma unroll
    for (int i = 0; i < 8; i++) { v[i] = __expf(v[i] - m); s += v[i]; }
#pragma unroll
    for (int o = 1; o < 64; o <<= 1) s += __shfl_xor(s, o, 64);
    __syncthreads();
    if ((tx & 63) == 0) red[tx >> 6] = s;
    __syncthreads();
    const float inv = 1.0f / (red[0] + red[1] + red[2] + red[3]);
#pragma unroll
    for (int i = 0; i < 8; i++) p[tx + 256 * i] = __float2bfloat16(v[i] * inv);
}

extern "C" void kernel_launch(void* const* d_in, const int* in_sizes, int n_in,
                              void* d_out, int out_size, void* d_ws, size_t ws_size,
                              hipStream_t stream)
{
    const int Bb = 8, Nn = 2048, DA = 768, DB = 1024;
    const long Mt = (long)Bb * Nn;   // 16384 tokens

    const float* x_a   = (const float*)d_in[0];
    const float* x_b   = (const float*)d_in[1];
    const float* sa_wq = (const float*)d_in[2];  const float* sa_bq = (const float*)d_in[3];
    const float* sa_wk = (const float*)d_in[4];  const float* sa_bk = (const float*)d_in[5];
    const float* sa_wv = (const float*)d_in[6];  const float* sa_bv = (const float*)d_in[7];
    const float* sa_wo = (const float*)d_in[8];  const float* sa_bo = (const float*)d_in[9];
    const float* ca_wq = (const float*)d_in[10]; const float* ca_bq = (const float*)d_in[11];
    const float* ca_wk = (const float*)d_in[12]; const float* ca_bk = (const float*)d_in[13];
    const float* ca_wv = (const float*)d_in[14]; const float* ca_bv = (const float*)d_in[15];
    const float* ca_wo = (const float*)d_in[16]; const float* ca_bo = (const float*)d_in[17];
    float* out = (float*)d_out;
    (void)in_sizes; (void)n_in; (void)out_size; (void)ws_size;

    // workspace carve-up (256B aligned): peak 207.5 MB (round-3 layout proven)
    char* ws = (char*)d_ws;
    size_t off = 0;
    auto alloc = [&](size_t bytes) -> bf* {
        bf* p = (bf*)(ws + off);
        off += (bytes + 255) & ~(size_t)255;
        return p;
    };
    bf* wqkvT = alloc((size_t)3 * DB * DB * 2);  // [3072,1024] concat q,k,v
    bf* woT   = alloc((size_t)DB * DB * 2);
    bf* cwqT  = alloc((size_t)DB * DA * 2);      // [1024,768]
    bf* ckvT  = alloc((size_t)2 * DB * DB * 2);  // [2048,1024] concat k,v
    bf* cwoT  = alloc((size_t)DB * DB * 2);
    bf* slA   = alloc((size_t)Mt * DB * 2);      // xbB -> xaB -> VcT
    bf* slQ   = alloc((size_t)Mt * DB * 2);      // Q   -> Xb
    bf* slK   = alloc((size_t)Mt * DB * 2);      // K   -> attn -> Qc
    bf* slV   = alloc((size_t)Mt * DB * 2);      // VT  -> Kc
    bf* S     = alloc((size_t)Bb * Nn * Nn * 2);

    const dim3 tb(32, 8);
    const dim3 blk(256);
    const long sQ = (long)Nn * DB;   // per-batch stride of [N,DB] / [DB,N]
    const long sS = (long)Nn * Nn;
    const float* nf = nullptr;
    const bf*    nb = nullptr;
    bf*          no = nullptr;

    // ---- ingestion: weight transposes (f32 -> bf16), concat layouts ----
    transpose_f32_bf16<<<dim3(DB/32, DB/32), tb, 0, stream>>>(sa_wq, wqkvT,                 DB, DB);
    transpose_f32_bf16<<<dim3(DB/32, DB/32), tb, 0, stream>>>(sa_wk, wqkvT + (size_t)DB*DB, DB, DB);
    transpose_f32_bf16<<<dim3(DB/32, DB/32), tb, 0, stream>>>(sa_wv, wqkvT + (size_t)2*DB*DB, DB, DB);
    transpose_f32_bf16<<<dim3(DB/32, DB/32), tb, 0, stream>>>(sa_wo, woT,  DB, DB);
    transpose_f32_bf16<<<dim3(DB/32, DA/32), tb, 0, stream>>>(ca_wq, cwqT, DA, DB);
    transpose_f32_bf16<<<dim3(DB/32, DB/32), tb, 0, stream>>>(ca_wk, ckvT,                 DB, DB);
    transpose_f32_bf16<<<dim3(DB/32, DB/32), tb, 0, stream>>>(ca_wv, ckvT + (size_t)DB*DB, DB, DB);
    transpose_f32_bf16<<<dim3(DB/32, DB/32), tb, 0, stream>>>(ca_wo, cwoT, DB, DB);

    // ---- self-attention ----
    cast_f32_bf16<<<dim3((unsigned)(Mt * DB / 8 / 256)), blk, 0, stream>>>(x_b, slA, Mt * DB);
    // fused QKV: Q->slQ, K->slK, V->slV (transposed per batch)
    gemm_bt<<<dim3(3*DB/BN, Mt/BM, 1), blk, 0, stream>>>(
        slA, wqkvT, sa_bq, sa_bk, sa_bv, nf, nb, slQ, slK, slV, nullptr,
        (int)Mt, 3*DB, DB, 1.0f, 0, 0, 0, 0b100, 3);
    // scores = (Q @ K^T) / 32
    gemm_bt<<<dim3(Nn/BN, Nn/BM, Bb), blk, 0, stream>>>(
        slQ, slK, nf, nf, nf, nf, nb, S, no, no, nullptr,
        Nn, Nn, DB, 0.03125f, sQ, sQ, sS, 0, 1);
    softmax_rows<<<dim3((unsigned)(Bb * Nn)), blk, 0, stream>>>(S);
    // attn = P @ V (VT as B^T) -> slK (K dead)
    gemm_bt<<<dim3(DB/BN, Nn/BM, Bb), blk, 0, stream>>>(
        S, slV, nf, nf, nf, nf, nb, slK, no, no, nullptr,
        Nn, DB, Nn, 1.0f, sS, sQ, sQ, 0, 1);
    // x_b_new = x_b(f32) + attn @ Wo + bo -> slQ (Q dead)
    gemm_bt<<<dim3(DB/BN, Mt/BM, 1), blk, 0, stream>>>(
        slK, woT, sa_bo, nf, nf, x_b, nb, slQ, no, no, nullptr,
        (int)Mt, DB, DB, 1.0f, 0, 0, 0, 0, 1);

    // ---- cross-attention ----
    cast_f32_bf16<<<dim3((unsigned)(Mt * DA / 8 / 256)), blk, 0, stream>>>(x_a, slA, Mt * DA);
    // Qc = xa @ cwq -> slK (attn dead)
    gemm_bt<<<dim3(DB/BN, Mt/BM, 1), blk, 0, stream>>>(
        slA, cwqT, ca_bq, nf, nf, nf, nb, slK, no, no, nullptr,
        (int)Mt, DB, DA, 1.0f, 0, 0, 0, 0, 1);
    // fused cKV from Xb(slQ): Kc->slV (VT dead), Vc->slA transposed (xaB dead)
    gemm_bt<<<dim3(2*DB/BN, Mt/BM, 1), blk, 0, stream>>>(
        slQ, ckvT, ca_bk, ca_bv, nf, nf, nb, slV, slA, no, nullptr,
        (int)Mt, 2*DB, DB, 1.0f, 0, 0, 0, 0b10, 2);
    // scores = (Qc @ Kc^T) / sqrt(768)
    gemm_bt<<<dim3(Nn/BN, Nn/BM, Bb), blk, 0, stream>>>(
        slK, slV, nf, nf, nf, nf, nb, S, no, no, nullptr,
        Nn, Nn, DB, 0.036084391824351615f, sQ, sQ, sS, 0, 1);
    softmax_rows<<<dim3((unsigned)(Bb * Nn)), blk, 0, stream>>>(S);
    // ca_attn = P @ Vc -> slV (Kc dead)
    gemm_bt<<<dim3(DB/BN, Nn/BM, Bb), blk, 0, stream>>>(
        S, slA, nf, nf, nf, nf, nb, slV, no, no, nullptr,
        Nn, DB, Nn, 1.0f, sS, sQ, sQ, 0, 1);
    // out(f32) = x_b_new(bf16, slQ) + ca_attn @ Wo + bo
    gemm_bt<<<dim3(DB/BN, Mt/BM, 1), blk, 0, stream>>>(
        slV, cwoT, ca_bo, nf, nf, nf, slQ, no, no, no, out,
        (int)Mt, DB, DB, 1.0f, 0, 0, 0, 0, 1);
}

// Round 6
// 1311.262 us; speedup vs baseline: 1.1721x; 1.0575x over previous
//
#include <hip/hip_runtime.h>
#include <hip/hip_bf16.h>

// Round 6: add a BN=64 GEMM variant (2x grid) for the five latency-bound
// grid-1024 dispatches (PV x2, out-proj x2, Qc). Evidence: r3->r4 showed 3x
// blocks -> 2.5x throughput at identical block structure (206->515 TF);
// 1024-block dispatches are parallelism-starved (4 blocks/CU queued).
// r5 null result: LDS swizzle left SQ_LDS_BANK_CONFLICT exactly 1.258e7 ->
// counter is structural, not ds_read-pattern; swizzle kept (neutral).
// f32 in/out per reference; bf16 MFMA internally. B=8, N=2048, DA=768, DB=1024.

#define AS1 __attribute__((address_space(1)))
#define AS3 __attribute__((address_space(3)))

typedef __attribute__((ext_vector_type(8))) short bf16x8;
typedef __attribute__((ext_vector_type(4))) float f32x4;

using bf = __hip_bfloat16;

#define BM 128
#define BN 128
#define BK 32

// ---------------- BN=128 kernel (QKV / scores / cKV) ----------------
// C = alpha * A[M,K] @ BT[Nc,K]^T.
// nseg==1: (+bias)(+resid32/resid16) -> C16 and/or C32, ldc=Nc, tstore bit0.
// nseg>1 : 1024-col segments -> {C16,C16b,C16c} w/ biases {bias,biasB,biasC};
//          tstore bit s stores segment s transposed per 2048-row batch.
__global__ __launch_bounds__(256) void gemm_bt(
    const bf* __restrict__ A, const bf* __restrict__ BT,
    const float* __restrict__ bias, const float* __restrict__ biasB,
    const float* __restrict__ biasC,
    const float* __restrict__ resid32, const bf* __restrict__ resid16,
    bf* __restrict__ C16, bf* __restrict__ C16b, bf* __restrict__ C16c,
    float* __restrict__ C32,
    int M, int Nc, int K, float alpha,
    long sA, long sB, long sC, int tstore, int nseg)
{
    __shared__ short As[BM * BK];
    __shared__ short Bs[BN * BK];

    const int tid  = threadIdx.x;
    const int wave = tid >> 6;
    const int lane = tid & 63;
    const int m0 = blockIdx.y * BM;
    const int n0 = blockIdx.x * BN;
    const long zC = (long)blockIdx.z * sC;
    A  += (long)blockIdx.z * sA;
    BT += (long)blockIdx.z * sB;

    const int wm = wave >> 1, wn = wave & 1;
    const int fl = lane & 15, qd = lane >> 4;

    f32x4 acc[4][4];
#pragma unroll
    for (int i = 0; i < 4; i++)
#pragma unroll
        for (int j = 0; j < 4; j++)
            acc[i][j] = (f32x4){0.f, 0.f, 0.f, 0.f};

    // Swizzled staging: slot s of row R holds global chunk ((s)-R-(R>>2))&3.
    const int R1 = wave * 32 + (lane >> 2);
    const int R2 = R1 + 16;
    const int sl = lane & 3;
    const int c1 = (sl - R1 - (R1 >> 2)) & 3;
    const int c2 = (sl - R2 - (R2 >> 2)) & 3;
    const long ldb = (long)K * 2;

    const char* gA1 = (const char*)A  + (long)(m0 + R1) * ldb + c1 * 16;
    const char* gA2 = (const char*)A  + (long)(m0 + R2) * ldb + c2 * 16;
    const char* gB1 = (const char*)BT + (long)(n0 + R1) * ldb + c1 * 16;
    const char* gB2 = (const char*)BT + (long)(n0 + R2) * ldb + c2 * 16;
    char* lA = (char*)As + wave * 2048;
    char* lB = (char*)Bs + wave * 2048;

    for (int k0 = 0; k0 < K; k0 += BK) {
        __builtin_amdgcn_global_load_lds((const AS1 void*)gA1, (AS3 void*)lA,          16, 0, 0);
        __builtin_amdgcn_global_load_lds((const AS1 void*)gA2, (AS3 void*)(lA + 1024), 16, 0, 0);
        __builtin_amdgcn_global_load_lds((const AS1 void*)gB1, (AS3 void*)lB,          16, 0, 0);
        __builtin_amdgcn_global_load_lds((const AS1 void*)gB2, (AS3 void*)(lB + 1024), 16, 0, 0);
        gA1 += BK * 2; gA2 += BK * 2; gB1 += BK * 2; gB2 += BK * 2;
        __syncthreads();

        bf16x8 af[4], bfr[4];
#pragma unroll
        for (int i = 0; i < 4; i++) {
            const int RA = wm * 64 + i * 16 + fl;
            const int RB = wn * 64 + i * 16 + fl;
            const int sA16 = (qd + RA + (RA >> 2)) & 3;
            const int sB16 = (qd + RB + (RB >> 2)) & 3;
            af[i]  = *(const bf16x8*)(As + RA * 32 + sA16 * 8);
            bfr[i] = *(const bf16x8*)(Bs + RB * 32 + sB16 * 8);
        }
#pragma unroll
        for (int i = 0; i < 4; i++)
#pragma unroll
            for (int j = 0; j < 4; j++)
                acc[i][j] = __builtin_amdgcn_mfma_f32_16x16x32_bf16(af[i], bfr[j], acc[i][j], 0, 0, 0);
        __syncthreads();
    }

    if (nseg == 1) {
        const long ldc = Nc;
#pragma unroll
        for (int i = 0; i < 4; i++) {
#pragma unroll
            for (int j = 0; j < 4; j++) {
#pragma unroll
                for (int r = 0; r < 4; r++) {
                    const int row = m0 + wm * 64 + i * 16 + qd * 4 + r;
                    const int col = n0 + wn * 64 + j * 16 + fl;
                    float v = acc[i][j][r] * alpha;
                    if (bias) v += bias[col];
                    if (tstore & 1) {
                        const long idx = (long)(row >> 11) * ((long)Nc * 2048)
                                       + (long)col * 2048 + (row & 2047);
                        C16[idx] = __float2bfloat16(v);
                    } else {
                        const long idx = zC + (long)row * ldc + col;
                        if (resid32) v += resid32[idx];
                        if (resid16) v += __bfloat162float(resid16[idx]);
                        if (C16) C16[idx] = __float2bfloat16(v);
                        if (C32) C32[idx] = v;
                    }
                }
            }
        }
    } else {
        const int seg = n0 >> 10;
        bf* dst = (seg == 0) ? C16 : ((seg == 1) ? C16b : C16c);
        const float* bseg = (seg == 0) ? bias : ((seg == 1) ? biasB : biasC);
        const int trans = (tstore >> seg) & 1;
        const int cb = n0 & 1023;
#pragma unroll
        for (int i = 0; i < 4; i++) {
#pragma unroll
            for (int j = 0; j < 4; j++) {
#pragma unroll
                for (int r = 0; r < 4; r++) {
                    const int row = m0 + wm * 64 + i * 16 + qd * 4 + r;
                    const int col = cb + wn * 64 + j * 16 + fl;
                    float v = acc[i][j][r] * alpha + bseg[col];
                    const long idx = trans
                        ? (long)(row >> 11) * (1024L * 2048) + (long)col * 2048 + (row & 2047)
                        : (long)row * 1024 + col;
                    dst[idx] = __float2bfloat16(v);
                }
            }
        }
    }
}

// ---------------- BN=64 kernel (PV / out-proj / Qc) ----------------
// 128x64 tile, 4 waves stacked vertically (32x64 per wave). 12 KB LDS.
// C = alpha * A @ BT^T (+bias)(+resid32/resid16) -> C16/C32. Batched via z.
__global__ __launch_bounds__(256) void gemm_bt64(
    const bf* __restrict__ A, const bf* __restrict__ BT,
    const float* __restrict__ bias,
    const float* __restrict__ resid32, const bf* __restrict__ resid16,
    bf* __restrict__ C16, float* __restrict__ C32,
    int M, int Nc, int K, float alpha,
    long sA, long sB, long sC)
{
    __shared__ short As[BM * BK];       // 8 KB
    __shared__ short Bs[64 * BK];       // 4 KB

    const int tid  = threadIdx.x;
    const int wave = tid >> 6;
    const int lane = tid & 63;
    const int m0 = blockIdx.y * BM;
    const int n0 = blockIdx.x * 64;
    const long zC = (long)blockIdx.z * sC;
    A  += (long)blockIdx.z * sA;
    BT += (long)blockIdx.z * sB;

    const int fl = lane & 15, qd = lane >> 4;

    f32x4 acc[2][4];
#pragma unroll
    for (int i = 0; i < 2; i++)
#pragma unroll
        for (int j = 0; j < 4; j++)
            acc[i][j] = (f32x4){0.f, 0.f, 0.f, 0.f};

    // A staging: wave w -> rows [w*32, w*32+32) (two 16-row loads).
    // B staging: wave w -> rows [w*16, w*16+16) (one load).
    const int R1 = wave * 32 + (lane >> 2);
    const int R2 = R1 + 16;
    const int RB1 = wave * 16 + (lane >> 2);
    const int sl = lane & 3;
    const int c1 = (sl - R1 - (R1 >> 2)) & 3;
    const int c2 = (sl - R2 - (R2 >> 2)) & 3;
    const int cB = (sl - RB1 - (RB1 >> 2)) & 3;
    const long ldb = (long)K * 2;

    const char* gA1 = (const char*)A  + (long)(m0 + R1) * ldb + c1 * 16;
    const char* gA2 = (const char*)A  + (long)(m0 + R2) * ldb + c2 * 16;
    const char* gB1 = (const char*)BT + (long)(n0 + RB1) * ldb + cB * 16;
    char* lA = (char*)As + wave * 2048;
    char* lB = (char*)Bs + wave * 1024;

    for (int k0 = 0; k0 < K; k0 += BK) {
        __builtin_amdgcn_global_load_lds((const AS1 void*)gA1, (AS3 void*)lA,          16, 0, 0);
        __builtin_amdgcn_global_load_lds((const AS1 void*)gA2, (AS3 void*)(lA + 1024), 16, 0, 0);
        __builtin_amdgcn_global_load_lds((const AS1 void*)gB1, (AS3 void*)lB,          16, 0, 0);
        gA1 += BK * 2; gA2 += BK * 2; gB1 += BK * 2;
        __syncthreads();

        bf16x8 af[2], bfr[4];
#pragma unroll
        for (int i = 0; i < 2; i++) {
            const int RA = wave * 32 + i * 16 + fl;
            const int sA16 = (qd + RA + (RA >> 2)) & 3;
            af[i] = *(const bf16x8*)(As + RA * 32 + sA16 * 8);
        }
#pragma unroll
        for (int j = 0; j < 4; j++) {
            const int RB = j * 16 + fl;
            const int sB16 = (qd + RB + (RB >> 2)) & 3;
            bfr[j] = *(const bf16x8*)(Bs + RB * 32 + sB16 * 8);
        }
#pragma unroll
        for (int i = 0; i < 2; i++)
#pragma unroll
            for (int j = 0; j < 4; j++)
                acc[i][j] = __builtin_amdgcn_mfma_f32_16x16x32_bf16(af[i], bfr[j], acc[i][j], 0, 0, 0);
        __syncthreads();
    }

    const long ldc = Nc;
#pragma unroll
    for (int i = 0; i < 2; i++) {
#pragma unroll
        for (int j = 0; j < 4; j++) {
#pragma unroll
            for (int r = 0; r < 4; r++) {
                const int row = m0 + wave * 32 + i * 16 + qd * 4 + r;
                const int col = n0 + j * 16 + fl;
                const long idx = zC + (long)row * ldc + col;
                float v = acc[i][j][r] * alpha;
                if (bias)    v += bias[col];
                if (resid32) v += resid32[idx];
                if (resid16) v += __bfloat162float(resid16[idx]);
                if (C16) C16[idx] = __float2bfloat16(v);
                if (C32) C32[idx] = v;
            }
        }
    }
}

// elementwise f32 -> bf16, n must be a multiple of 8
__global__ __launch_bounds__(256) void cast_f32_bf16(
    const float* __restrict__ in, bf* __restrict__ out, long n)
{
    long i = ((long)blockIdx.x * 256 + threadIdx.x) * 8;
    if (i >= n) return;
    float4 a = *(const float4*)(in + i);
    float4 b = *(const float4*)(in + i + 4);
    bf o[8] = {__float2bfloat16(a.x), __float2bfloat16(a.y),
               __float2bfloat16(a.z), __float2bfloat16(a.w),
               __float2bfloat16(b.x), __float2bfloat16(b.y),
               __float2bfloat16(b.z), __float2bfloat16(b.w)};
    *(bf16x8*)(out + i) = *(bf16x8*)o;
}

// W[R,C] f32 -> WT[C,R] bf16
__global__ __launch_bounds__(256) void transpose_f32_bf16(
    const float* __restrict__ in, bf* __restrict__ out, int R, int C)
{
    __shared__ bf t[32][33];
    const int c0 = blockIdx.x * 32, r0 = blockIdx.y * 32;
    const int tx = threadIdx.x, ty = threadIdx.y;
#pragma unroll
    for (int i = ty; i < 32; i += 8)
        t[i][tx] = __float2bfloat16(in[(long)(r0 + i) * C + c0 + tx]);
    __syncthreads();
#pragma unroll
    for (int i = ty; i < 32; i += 8)
        out[(long)(c0 + i) * R + r0 + tx] = t[tx][i];
}

// In-place row softmax over 2048 bf16 cols; one 256-thread block per row.
__global__ __launch_bounds__(256) void softmax_rows(bf* __restrict__ S)
{
    const long row = blockIdx.x;
    bf* p = S + row * 2048;
    const int tx = threadIdx.x;

    float v[8];
    float m = -3.0e38f;
#pragma unroll
    for (int i = 0; i < 8; i++) {
        v[i] = __bfloat162float(p[tx + 256 * i]);
        m = fmaxf(m, v[i]);
    }
    __shared__ float red[4];
#pragma unroll
    for (int o = 1; o < 64; o <<= 1) m = fmaxf(m, __shfl_xor(m, o, 64));
    if ((tx & 63) == 0) red[tx >> 6] = m;
    __syncthreads();
    m = fmaxf(fmaxf(red[0], red[1]), fmaxf(red[2], red[3]));

    float s = 0.f;
#pragma unroll
    for (int i = 0; i < 8; i++) { v[i] = __expf(v[i] - m); s += v[i]; }
#pragma unroll
    for (int o = 1; o < 64; o <<= 1) s += __shfl_xor(s, o, 64);
    __syncthreads();
    if ((tx & 63) == 0) red[tx >> 6] = s;
    __syncthreads();
    const float inv = 1.0f / (red[0] + red[1] + red[2] + red[3]);
#pragma unroll
    for (int i = 0; i < 8; i++) p[tx + 256 * i] = __float2bfloat16(v[i] * inv);
}

extern "C" void kernel_launch(void* const* d_in, const int* in_sizes, int n_in,
                              void* d_out, int out_size, void* d_ws, size_t ws_size,
                              hipStream_t stream)
{
    const int Bb = 8, Nn = 2048, DA = 768, DB = 1024;
    const long Mt = (long)Bb * Nn;   // 16384 tokens

    const float* x_a   = (const float*)d_in[0];
    const float* x_b   = (const float*)d_in[1];
    const float* sa_wq = (const float*)d_in[2];  const float* sa_bq = (const float*)d_in[3];
    const float* sa_wk = (const float*)d_in[4];  const float* sa_bk = (const float*)d_in[5];
    const float* sa_wv = (const float*)d_in[6];  const float* sa_bv = (const float*)d_in[7];
    const float* sa_wo = (const float*)d_in[8];  const float* sa_bo = (const float*)d_in[9];
    const float* ca_wq = (const float*)d_in[10]; const float* ca_bq = (const float*)d_in[11];
    const float* ca_wk = (const float*)d_in[12]; const float* ca_bk = (const float*)d_in[13];
    const float* ca_wv = (const float*)d_in[14]; const float* ca_bv = (const float*)d_in[15];
    const float* ca_wo = (const float*)d_in[16]; const float* ca_bo = (const float*)d_in[17];
    float* out = (float*)d_out;
    (void)in_sizes; (void)n_in; (void)out_size; (void)ws_size;

    // workspace carve-up (256B aligned): peak 207.5 MB (r3 layout proven)
    char* ws = (char*)d_ws;
    size_t off = 0;
    auto alloc = [&](size_t bytes) -> bf* {
        bf* p = (bf*)(ws + off);
        off += (bytes + 255) & ~(size_t)255;
        return p;
    };
    bf* wqkvT = alloc((size_t)3 * DB * DB * 2);  // [3072,1024] concat q,k,v
    bf* woT   = alloc((size_t)DB * DB * 2);
    bf* cwqT  = alloc((size_t)DB * DA * 2);      // [1024,768]
    bf* ckvT  = alloc((size_t)2 * DB * DB * 2);  // [2048,1024] concat k,v
    bf* cwoT  = alloc((size_t)DB * DB * 2);
    bf* slA   = alloc((size_t)Mt * DB * 2);      // xbB -> xaB -> VcT
    bf* slQ   = alloc((size_t)Mt * DB * 2);      // Q   -> Xb
    bf* slK   = alloc((size_t)Mt * DB * 2);      // K   -> attn -> Qc
    bf* slV   = alloc((size_t)Mt * DB * 2);      // VT  -> Kc
    bf* S     = alloc((size_t)Bb * Nn * Nn * 2);

    const dim3 tb(32, 8);
    const dim3 blk(256);
    const long sQ = (long)Nn * DB;
    const long sS = (long)Nn * Nn;
    const float* nf = nullptr;
    const bf*    nb = nullptr;
    bf*          no = nullptr;

    // ---- ingestion: weight transposes (f32 -> bf16), concat layouts ----
    transpose_f32_bf16<<<dim3(DB/32, DB/32), tb, 0, stream>>>(sa_wq, wqkvT,                 DB, DB);
    transpose_f32_bf16<<<dim3(DB/32, DB/32), tb, 0, stream>>>(sa_wk, wqkvT + (size_t)DB*DB, DB, DB);
    transpose_f32_bf16<<<dim3(DB/32, DB/32), tb, 0, stream>>>(sa_wv, wqkvT + (size_t)2*DB*DB, DB, DB);
    transpose_f32_bf16<<<dim3(DB/32, DB/32), tb, 0, stream>>>(sa_wo, woT,  DB, DB);
    transpose_f32_bf16<<<dim3(DB/32, DA/32), tb, 0, stream>>>(ca_wq, cwqT, DA, DB);
    transpose_f32_bf16<<<dim3(DB/32, DB/32), tb, 0, stream>>>(ca_wk, ckvT,                 DB, DB);
    transpose_f32_bf16<<<dim3(DB/32, DB/32), tb, 0, stream>>>(ca_wv, ckvT + (size_t)DB*DB, DB, DB);
    transpose_f32_bf16<<<dim3(DB/32, DB/32), tb, 0, stream>>>(ca_wo, cwoT, DB, DB);

    // ---- self-attention ----
    cast_f32_bf16<<<dim3((unsigned)(Mt * DB / 8 / 256)), blk, 0, stream>>>(x_b, slA, Mt * DB);
    // fused QKV: Q->slQ, K->slK, V->slV (transposed per batch)
    gemm_bt<<<dim3(3*DB/BN, Mt/BM, 1), blk, 0, stream>>>(
        slA, wqkvT, sa_bq, sa_bk, sa_bv, nf, nb, slQ, slK, slV, nullptr,
        (int)Mt, 3*DB, DB, 1.0f, 0, 0, 0, 0b100, 3);
    // scores = (Q @ K^T) / 32
    gemm_bt<<<dim3(Nn/BN, Nn/BM, Bb), blk, 0, stream>>>(
        slQ, slK, nf, nf, nf, nf, nb, S, no, no, nullptr,
        Nn, Nn, DB, 0.03125f, sQ, sQ, sS, 0, 1);
    softmax_rows<<<dim3((unsigned)(Bb * Nn)), blk, 0, stream>>>(S);
    // attn = P @ V (VT as B^T) -> slK (K dead)   [BN=64: 2048 blocks]
    gemm_bt64<<<dim3(DB/64, Nn/BM, Bb), blk, 0, stream>>>(
        S, slV, nf, nf, nb, slK, nullptr, Nn, DB, Nn, 1.0f, sS, sQ, sQ);
    // x_b_new = x_b(f32) + attn @ Wo + bo -> slQ (Q dead)   [BN=64]
    gemm_bt64<<<dim3(DB/64, Mt/BM, 1), blk, 0, stream>>>(
        slK, woT, sa_bo, x_b, nb, slQ, nullptr, (int)Mt, DB, DB, 1.0f, 0, 0, 0);

    // ---- cross-attention ----
    cast_f32_bf16<<<dim3((unsigned)(Mt * DA / 8 / 256)), blk, 0, stream>>>(x_a, slA, Mt * DA);
    // Qc = xa @ cwq -> slK (attn dead)   [BN=64]
    gemm_bt64<<<dim3(DB/64, Mt/BM, 1), blk, 0, stream>>>(
        slA, cwqT, ca_bq, nf, nb, slK, nullptr, (int)Mt, DB, DA, 1.0f, 0, 0, 0);
    // fused cKV from Xb(slQ): Kc->slV (VT dead), Vc->slA transposed (xaB dead)
    gemm_bt<<<dim3(2*DB/BN, Mt/BM, 1), blk, 0, stream>>>(
        slQ, ckvT, ca_bk, ca_bv, nf, nf, nb, slV, slA, no, nullptr,
        (int)Mt, 2*DB, DB, 1.0f, 0, 0, 0, 0b10, 2);
    // scores = (Qc @ Kc^T) / sqrt(768)
    gemm_bt<<<dim3(Nn/BN, Nn/BM, Bb), blk, 0, stream>>>(
        slK, slV, nf, nf, nf, nf, nb, S, no, no, nullptr,
        Nn, Nn, DB, 0.036084391824351615f, sQ, sQ, sS, 0, 1);
    softmax_rows<<<dim3((unsigned)(Bb * Nn)), blk, 0, stream>>>(S);
    // ca_attn = P @ Vc -> slV (Kc dead)   [BN=64]
    gemm_bt64<<<dim3(DB/64, Nn/BM, Bb), blk, 0, stream>>>(
        S, slA, nf, nf, nb, slV, nullptr, Nn, DB, Nn, 1.0f, sS, sQ, sQ);
    // out(f32) = x_b_new(bf16, slQ) + ca_attn @ Wo + bo   [BN=64]
    gemm_bt64<<<dim3(DB/64, Mt/BM, 1), blk, 0, stream>>>(
        slV, cwoT, ca_bo, nf, slQ, no, out, (int)Mt, DB, DB, 1.0f, 0, 0, 0);
}

// Round 7
// 1186.964 us; speedup vs baseline: 1.2948x; 1.1047x over previous
//
#include <hip/hip_runtime.h>
#include <hip/hip_bf16.h>

// Round 7: BK=32 -> BK=64. r6 model: block lifetime ~16 µs vs ~1 µs MFMA work
// -> dominated by 32 per-iter vmcnt(0) barrier drains (K-loop latency-bound,
// only ~2.25 blocks/CU resident to cover). Halving the iteration count halves
// the drains. LDS 32 KB (5 blocks/CU), fragments read per k-half to cap VGPRs.
// 8-slot XOR swizzle keeps LDS reads 2-way (free). Accumulation order is
// unchanged -> bit-identical output vs r6.
// f32 in/out per reference; bf16 MFMA internally. B=8, N=2048, DA=768, DB=1024.

#define AS1 __attribute__((address_space(1)))
#define AS3 __attribute__((address_space(3)))

typedef __attribute__((ext_vector_type(8))) short bf16x8;
typedef __attribute__((ext_vector_type(4))) float f32x4;

using bf = __hip_bfloat16;

#define BM 128
#define BN 128
#define BK 64   // 128 B per tile row = 8 chunks of 16 B

// ---------------- BN=128 kernel (QKV / scores / cKV) ----------------
// C = alpha * A[M,K] @ BT[Nc,K]^T.
// nseg==1: (+bias)(+resid32/resid16) -> C16 and/or C32, ldc=Nc, tstore bit0.
// nseg>1 : 1024-col segments -> {C16,C16b,C16c} w/ biases {bias,biasB,biasC};
//          tstore bit s stores segment s transposed per 2048-row batch.
__global__ __launch_bounds__(256) void gemm_bt(
    const bf* __restrict__ A, const bf* __restrict__ BT,
    const float* __restrict__ bias, const float* __restrict__ biasB,
    const float* __restrict__ biasC,
    const float* __restrict__ resid32, const bf* __restrict__ resid16,
    bf* __restrict__ C16, bf* __restrict__ C16b, bf* __restrict__ C16c,
    float* __restrict__ C32,
    int M, int Nc, int K, float alpha,
    long sA, long sB, long sC, int tstore, int nseg)
{
    __shared__ short As[BM * BK];   // 16 KB
    __shared__ short Bs[BN * BK];   // 16 KB

    const int tid  = threadIdx.x;
    const int wave = tid >> 6;
    const int lane = tid & 63;
    const int m0 = blockIdx.y * BM;
    const int n0 = blockIdx.x * BN;
    const long zC = (long)blockIdx.z * sC;
    A  += (long)blockIdx.z * sA;
    BT += (long)blockIdx.z * sB;

    const int wm = wave >> 1, wn = wave & 1;
    const int fl = lane & 15, qd = lane >> 4;

    f32x4 acc[4][4];
#pragma unroll
    for (int i = 0; i < 4; i++)
#pragma unroll
        for (int j = 0; j < 4; j++)
            acc[i][j] = (f32x4){0.f, 0.f, 0.f, 0.f};

    // Staging: wave w -> rows [w*32, w*32+32), 4 loads of 8 rows each.
    // Lane l of load li lands at LDS row w*32+li*8+(l>>3), slot l&7; that slot
    // must hold global chunk c = (l&7) ^ (R&7) = (l&7)^(l>>3) (R&7 == l>>3).
    const int sr = lane >> 3;            // sub-row within 8-row group
    const int sc = (lane & 7) ^ sr;      // swizzled chunk this lane fetches
    const long ldb = (long)K * 2;        // row bytes for A and BT

    const char* gA0 = (const char*)A  + (long)(m0 + wave * 32 + sr) * ldb + sc * 16;
    const char* gB0 = (const char*)BT + (long)(n0 + wave * 32 + sr) * ldb + sc * 16;
    char* lA = (char*)As + wave * 4096;
    char* lB = (char*)Bs + wave * 4096;

    for (int k0 = 0; k0 < K; k0 += BK) {
#pragma unroll
        for (int li = 0; li < 4; li++)
            __builtin_amdgcn_global_load_lds((const AS1 void*)(gA0 + (long)li * 8 * ldb),
                                             (AS3 void*)(lA + li * 1024), 16, 0, 0);
#pragma unroll
        for (int li = 0; li < 4; li++)
            __builtin_amdgcn_global_load_lds((const AS1 void*)(gB0 + (long)li * 8 * ldb),
                                             (AS3 void*)(lB + li * 1024), 16, 0, 0);
        gA0 += BK * 2;
        gB0 += BK * 2;
        __syncthreads();   // drains vmcnt -> staging visible

#pragma unroll
        for (int h = 0; h < 2; h++) {   // two K-halves of 32
            bf16x8 af[4], bfr[4];
#pragma unroll
            for (int i = 0; i < 4; i++) {
                const int RA = wm * 64 + i * 16 + fl;
                const int RB = wn * 64 + i * 16 + fl;
                const int slot = ((h << 2) | qd) ^ (fl & 7);  // R&7 == fl&7
                af[i]  = *(const bf16x8*)(As + RA * 64 + slot * 8);
                bfr[i] = *(const bf16x8*)(Bs + RB * 64 + slot * 8);
            }
#pragma unroll
            for (int i = 0; i < 4; i++)
#pragma unroll
                for (int j = 0; j < 4; j++)
                    acc[i][j] = __builtin_amdgcn_mfma_f32_16x16x32_bf16(af[i], bfr[j], acc[i][j], 0, 0, 0);
        }
        __syncthreads();   // protect LDS before next staging
    }

    // Epilogue: C/D layout col = lane&15, row = qd*4 + r (verified m89/m91).
    if (nseg == 1) {
        const long ldc = Nc;
#pragma unroll
        for (int i = 0; i < 4; i++) {
#pragma unroll
            for (int j = 0; j < 4; j++) {
#pragma unroll
                for (int r = 0; r < 4; r++) {
                    const int row = m0 + wm * 64 + i * 16 + qd * 4 + r;
                    const int col = n0 + wn * 64 + j * 16 + fl;
                    float v = acc[i][j][r] * alpha;
                    if (bias) v += bias[col];
                    if (tstore & 1) {
                        const long idx = (long)(row >> 11) * ((long)Nc * 2048)
                                       + (long)col * 2048 + (row & 2047);
                        C16[idx] = __float2bfloat16(v);
                    } else {
                        const long idx = zC + (long)row * ldc + col;
                        if (resid32) v += resid32[idx];
                        if (resid16) v += __bfloat162float(resid16[idx]);
                        if (C16) C16[idx] = __float2bfloat16(v);
                        if (C32) C32[idx] = v;
                    }
                }
            }
        }
    } else {
        const int seg = n0 >> 10;
        bf* dst = (seg == 0) ? C16 : ((seg == 1) ? C16b : C16c);
        const float* bseg = (seg == 0) ? bias : ((seg == 1) ? biasB : biasC);
        const int trans = (tstore >> seg) & 1;
        const int cb = n0 & 1023;
#pragma unroll
        for (int i = 0; i < 4; i++) {
#pragma unroll
            for (int j = 0; j < 4; j++) {
#pragma unroll
                for (int r = 0; r < 4; r++) {
                    const int row = m0 + wm * 64 + i * 16 + qd * 4 + r;
                    const int col = cb + wn * 64 + j * 16 + fl;
                    float v = acc[i][j][r] * alpha + bseg[col];
                    const long idx = trans
                        ? (long)(row >> 11) * (1024L * 2048) + (long)col * 2048 + (row & 2047)
                        : (long)row * 1024 + col;
                    dst[idx] = __float2bfloat16(v);
                }
            }
        }
    }
}

// ---------------- BN=64 kernel (PV / out-proj / Qc) ----------------
// 128x64 tile, 4 waves stacked vertically (32x64 per wave). 24 KB LDS.
__global__ __launch_bounds__(256) void gemm_bt64(
    const bf* __restrict__ A, const bf* __restrict__ BT,
    const float* __restrict__ bias,
    const float* __restrict__ resid32, const bf* __restrict__ resid16,
    bf* __restrict__ C16, float* __restrict__ C32,
    int M, int Nc, int K, float alpha,
    long sA, long sB, long sC)
{
    __shared__ short As[BM * BK];   // 16 KB
    __shared__ short Bs[64 * BK];   // 8 KB

    const int tid  = threadIdx.x;
    const int wave = tid >> 6;
    const int lane = tid & 63;
    const int m0 = blockIdx.y * BM;
    const int n0 = blockIdx.x * 64;
    const long zC = (long)blockIdx.z * sC;
    A  += (long)blockIdx.z * sA;
    BT += (long)blockIdx.z * sB;

    const int fl = lane & 15, qd = lane >> 4;

    f32x4 acc[2][4];
#pragma unroll
    for (int i = 0; i < 2; i++)
#pragma unroll
        for (int j = 0; j < 4; j++)
            acc[i][j] = (f32x4){0.f, 0.f, 0.f, 0.f};

    const int sr = lane >> 3;
    const int sc = (lane & 7) ^ sr;
    const long ldb = (long)K * 2;

    // A: wave w -> rows [w*32, w*32+32), 4 loads. B: rows [w*16, w*16+16), 2 loads.
    const char* gA0 = (const char*)A  + (long)(m0 + wave * 32 + sr) * ldb + sc * 16;
    const char* gB0 = (const char*)BT + (long)(n0 + wave * 16 + sr) * ldb + sc * 16;
    char* lA = (char*)As + wave * 4096;
    char* lB = (char*)Bs + wave * 2048;

    for (int k0 = 0; k0 < K; k0 += BK) {
#pragma unroll
        for (int li = 0; li < 4; li++)
            __builtin_amdgcn_global_load_lds((const AS1 void*)(gA0 + (long)li * 8 * ldb),
                                             (AS3 void*)(lA + li * 1024), 16, 0, 0);
#pragma unroll
        for (int li = 0; li < 2; li++)
            __builtin_amdgcn_global_load_lds((const AS1 void*)(gB0 + (long)li * 8 * ldb),
                                             (AS3 void*)(lB + li * 1024), 16, 0, 0);
        gA0 += BK * 2;
        gB0 += BK * 2;
        __syncthreads();

#pragma unroll
        for (int h = 0; h < 2; h++) {
            bf16x8 af[2], bfr[4];
#pragma unroll
            for (int i = 0; i < 2; i++) {
                const int RA = wave * 32 + i * 16 + fl;
                const int slot = ((h << 2) | qd) ^ (fl & 7);
                af[i] = *(const bf16x8*)(As + RA * 64 + slot * 8);
            }
#pragma unroll
            for (int j = 0; j < 4; j++) {
                const int RB = j * 16 + fl;
                const int slot = ((h << 2) | qd) ^ (fl & 7);
                bfr[j] = *(const bf16x8*)(Bs + RB * 64 + slot * 8);
            }
#pragma unroll
            for (int i = 0; i < 2; i++)
#pragma unroll
                for (int j = 0; j < 4; j++)
                    acc[i][j] = __builtin_amdgcn_mfma_f32_16x16x32_bf16(af[i], bfr[j], acc[i][j], 0, 0, 0);
        }
        __syncthreads();
    }

    const long ldc = Nc;
#pragma unroll
    for (int i = 0; i < 2; i++) {
#pragma unroll
        for (int j = 0; j < 4; j++) {
#pragma unroll
            for (int r = 0; r < 4; r++) {
                const int row = m0 + wave * 32 + i * 16 + qd * 4 + r;
                const int col = n0 + j * 16 + fl;
                const long idx = zC + (long)row * ldc + col;
                float v = acc[i][j][r] * alpha;
                if (bias)    v += bias[col];
                if (resid32) v += resid32[idx];
                if (resid16) v += __bfloat162float(resid16[idx]);
                if (C16) C16[idx] = __float2bfloat16(v);
                if (C32) C32[idx] = v;
            }
        }
    }
}

// elementwise f32 -> bf16, n must be a multiple of 8
__global__ __launch_bounds__(256) void cast_f32_bf16(
    const float* __restrict__ in, bf* __restrict__ out, long n)
{
    long i = ((long)blockIdx.x * 256 + threadIdx.x) * 8;
    if (i >= n) return;
    float4 a = *(const float4*)(in + i);
    float4 b = *(const float4*)(in + i + 4);
    bf o[8] = {__float2bfloat16(a.x), __float2bfloat16(a.y),
               __float2bfloat16(a.z), __float2bfloat16(a.w),
               __float2bfloat16(b.x), __float2bfloat16(b.y),
               __float2bfloat16(b.z), __float2bfloat16(b.w)};
    *(bf16x8*)(out + i) = *(bf16x8*)o;
}

// W[R,C] f32 -> WT[C,R] bf16
__global__ __launch_bounds__(256) void transpose_f32_bf16(
    const float* __restrict__ in, bf* __restrict__ out, int R, int C)
{
    __shared__ bf t[32][33];
    const int c0 = blockIdx.x * 32, r0 = blockIdx.y * 32;
    const int tx = threadIdx.x, ty = threadIdx.y;
#pragma unroll
    for (int i = ty; i < 32; i += 8)
        t[i][tx] = __float2bfloat16(in[(long)(r0 + i) * C + c0 + tx]);
    __syncthreads();
#pragma unroll
    for (int i = ty; i < 32; i += 8)
        out[(long)(c0 + i) * R + r0 + tx] = t[tx][i];
}

// In-place row softmax over 2048 bf16 cols; one 256-thread block per row.
__global__ __launch_bounds__(256) void softmax_rows(bf* __restrict__ S)
{
    const long row = blockIdx.x;
    bf* p = S + row * 2048;
    const int tx = threadIdx.x;

    float v[8];
    float m = -3.0e38f;
#pragma unroll
    for (int i = 0; i < 8; i++) {
        v[i] = __bfloat162float(p[tx + 256 * i]);
        m = fmaxf(m, v[i]);
    }
    __shared__ float red[4];
#pragma unroll
    for (int o = 1; o < 64; o <<= 1) m = fmaxf(m, __shfl_xor(m, o, 64));
    if ((tx & 63) == 0) red[tx >> 6] = m;
    __syncthreads();
    m = fmaxf(fmaxf(red[0], red[1]), fmaxf(red[2], red[3]));

    float s = 0.f;
#pragma unroll
    for (int i = 0; i < 8; i++) { v[i] = __expf(v[i] - m); s += v[i]; }
#pragma unroll
    for (int o = 1; o < 64; o <<= 1) s += __shfl_xor(s, o, 64);
    __syncthreads();
    if ((tx & 63) == 0) red[tx >> 6] = s;
    __syncthreads();
    const float inv = 1.0f / (red[0] + red[1] + red[2] + red[3]);
#pragma unroll
    for (int i = 0; i < 8; i++) p[tx + 256 * i] = __float2bfloat16(v[i] * inv);
}

extern "C" void kernel_launch(void* const* d_in, const int* in_sizes, int n_in,
                              void* d_out, int out_size, void* d_ws, size_t ws_size,
                              hipStream_t stream)
{
    const int Bb = 8, Nn = 2048, DA = 768, DB = 1024;
    const long Mt = (long)Bb * Nn;   // 16384 tokens

    const float* x_a   = (const float*)d_in[0];
    const float* x_b   = (const float*)d_in[1];
    const float* sa_wq = (const float*)d_in[2];  const float* sa_bq = (const float*)d_in[3];
    const float* sa_wk = (const float*)d_in[4];  const float* sa_bk = (const float*)d_in[5];
    const float* sa_wv = (const float*)d_in[6];  const float* sa_bv = (const float*)d_in[7];
    const float* sa_wo = (const float*)d_in[8];  const float* sa_bo = (const float*)d_in[9];
    const float* ca_wq = (const float*)d_in[10]; const float* ca_bq = (const float*)d_in[11];
    const float* ca_wk = (const float*)d_in[12]; const float* ca_bk = (const float*)d_in[13];
    const float* ca_wv = (const float*)d_in[14]; const float* ca_bv = (const float*)d_in[15];
    const float* ca_wo = (const float*)d_in[16]; const float* ca_bo = (const float*)d_in[17];
    float* out = (float*)d_out;
    (void)in_sizes; (void)n_in; (void)out_size; (void)ws_size;

    // workspace carve-up (256B aligned): peak 207.5 MB (r3 layout proven)
    char* ws = (char*)d_ws;
    size_t off = 0;
    auto alloc = [&](size_t bytes) -> bf* {
        bf* p = (bf*)(ws + off);
        off += (bytes + 255) & ~(size_t)255;
        return p;
    };
    bf* wqkvT = alloc((size_t)3 * DB * DB * 2);  // [3072,1024] concat q,k,v
    bf* woT   = alloc((size_t)DB * DB * 2);
    bf* cwqT  = alloc((size_t)DB * DA * 2);      // [1024,768]
    bf* ckvT  = alloc((size_t)2 * DB * DB * 2);  // [2048,1024] concat k,v
    bf* cwoT  = alloc((size_t)DB * DB * 2);
    bf* slA   = alloc((size_t)Mt * DB * 2);      // xbB -> xaB -> VcT
    bf* slQ   = alloc((size_t)Mt * DB * 2);      // Q   -> Xb
    bf* slK   = alloc((size_t)Mt * DB * 2);      // K   -> attn -> Qc
    bf* slV   = alloc((size_t)Mt * DB * 2);      // VT  -> Kc
    bf* S     = alloc((size_t)Bb * Nn * Nn * 2);

    const dim3 tb(32, 8);
    const dim3 blk(256);
    const long sQ = (long)Nn * DB;
    const long sS = (long)Nn * Nn;
    const float* nf = nullptr;
    const bf*    nb = nullptr;
    bf*          no = nullptr;

    // ---- ingestion: weight transposes (f32 -> bf16), concat layouts ----
    transpose_f32_bf16<<<dim3(DB/32, DB/32), tb, 0, stream>>>(sa_wq, wqkvT,                 DB, DB);
    transpose_f32_bf16<<<dim3(DB/32, DB/32), tb, 0, stream>>>(sa_wk, wqkvT + (size_t)DB*DB, DB, DB);
    transpose_f32_bf16<<<dim3(DB/32, DB/32), tb, 0, stream>>>(sa_wv, wqkvT + (size_t)2*DB*DB, DB, DB);
    transpose_f32_bf16<<<dim3(DB/32, DB/32), tb, 0, stream>>>(sa_wo, woT,  DB, DB);
    transpose_f32_bf16<<<dim3(DB/32, DA/32), tb, 0, stream>>>(ca_wq, cwqT, DA, DB);
    transpose_f32_bf16<<<dim3(DB/32, DB/32), tb, 0, stream>>>(ca_wk, ckvT,                 DB, DB);
    transpose_f32_bf16<<<dim3(DB/32, DB/32), tb, 0, stream>>>(ca_wv, ckvT + (size_t)DB*DB, DB, DB);
    transpose_f32_bf16<<<dim3(DB/32, DB/32), tb, 0, stream>>>(ca_wo, cwoT, DB, DB);

    // ---- self-attention ----
    cast_f32_bf16<<<dim3((unsigned)(Mt * DB / 8 / 256)), blk, 0, stream>>>(x_b, slA, Mt * DB);
    // fused QKV: Q->slQ, K->slK, V->slV (transposed per batch)
    gemm_bt<<<dim3(3*DB/BN, Mt/BM, 1), blk, 0, stream>>>(
        slA, wqkvT, sa_bq, sa_bk, sa_bv, nf, nb, slQ, slK, slV, nullptr,
        (int)Mt, 3*DB, DB, 1.0f, 0, 0, 0, 0b100, 3);
    // scores = (Q @ K^T) / 32
    gemm_bt<<<dim3(Nn/BN, Nn/BM, Bb), blk, 0, stream>>>(
        slQ, slK, nf, nf, nf, nf, nb, S, no, no, nullptr,
        Nn, Nn, DB, 0.03125f, sQ, sQ, sS, 0, 1);
    softmax_rows<<<dim3((unsigned)(Bb * Nn)), blk, 0, stream>>>(S);
    // attn = P @ V (VT as B^T) -> slK (K dead)   [BN=64: 2048 blocks]
    gemm_bt64<<<dim3(DB/64, Nn/BM, Bb), blk, 0, stream>>>(
        S, slV, nf, nf, nb, slK, nullptr, Nn, DB, Nn, 1.0f, sS, sQ, sQ);
    // x_b_new = x_b(f32) + attn @ Wo + bo -> slQ (Q dead)   [BN=64]
    gemm_bt64<<<dim3(DB/64, Mt/BM, 1), blk, 0, stream>>>(
        slK, woT, sa_bo, x_b, nb, slQ, nullptr, (int)Mt, DB, DB, 1.0f, 0, 0, 0);

    // ---- cross-attention ----
    cast_f32_bf16<<<dim3((unsigned)(Mt * DA / 8 / 256)), blk, 0, stream>>>(x_a, slA, Mt * DA);
    // Qc = xa @ cwq -> slK (attn dead)   [BN=64; K=768 = 12 BK-iters]
    gemm_bt64<<<dim3(DB/64, Mt/BM, 1), blk, 0, stream>>>(
        slA, cwqT, ca_bq, nf, nb, slK, nullptr, (int)Mt, DB, DA, 1.0f, 0, 0, 0);
    // fused cKV from Xb(slQ): Kc->slV (VT dead), Vc->slA transposed (xaB dead)
    gemm_bt<<<dim3(2*DB/BN, Mt/BM, 1), blk, 0, stream>>>(
        slQ, ckvT, ca_bk, ca_bv, nf, nf, nb, slV, slA, no, nullptr,
        (int)Mt, 2*DB, DB, 1.0f, 0, 0, 0, 0b10, 2);
    // scores = (Qc @ Kc^T) / sqrt(768)
    gemm_bt<<<dim3(Nn/BN, Nn/BM, Bb), blk, 0, stream>>>(
        slK, slV, nf, nf, nf, nf, nb, S, no, no, nullptr,
        Nn, Nn, DB, 0.036084391824351615f, sQ, sQ, sS, 0, 1);
    softmax_rows<<<dim3((unsigned)(Bb * Nn)), blk, 0, stream>>>(S);
    // ca_attn = P @ Vc -> slV (Kc dead)   [BN=64]
    gemm_bt64<<<dim3(DB/64, Nn/BM, Bb), blk, 0, stream>>>(
        S, slA, nf, nf, nb, slV, nullptr, Nn, DB, Nn, 1.0f, sS, sQ, sQ);
    // out(f32) = x_b_new(bf16, slQ) + ca_attn @ Wo + bo   [BN=64]
    gemm_bt64<<<dim3(DB/64, Mt/BM, 1), blk, 0, stream>>>(
        slV, cwoT, ca_bo, nf, slQ, no, out, (int)Mt, DB, DB, 1.0f, 0, 0, 0);
}